// Round 6
// baseline (591.818 us; speedup 1.0000x reference)
//
#include <hip/hip_runtime.h>

#define B_    64
#define L_    2048
#define D_    512
#define VP_   50258          // vocab+1 rows
#define NSLAB 256
#define RPB   197            // ceil(VP_/NSLAB)

// workspace offsets (in floats)
#define OFF_WA   3216512     // VP_*B_
#define OFF_SC   6433024     // 2*VP_*B_
#define OFF_PART 9649536     // 3*VP_*B_   (memset covers [0, OFF_PART))
#define OFF_H    18038144    // OFF_PART + 512*64*256
#define OFF_V    18070912    // OFF_H + 64*512

// lane0-valid sum
__device__ __forceinline__ float wave_sum(float x) {
#pragma unroll
  for (int off = 32; off > 0; off >>= 1) x += __shfl_down(x, off, 64);
  return x;
}

// ---------- K1: histogram cnt[v][b] ----------
__global__ __launch_bounds__(256) void k_hist(const int* __restrict__ tok,
                                              unsigned int* __restrict__ cnt) {
  const int idx = blockIdx.x * 256 + threadIdx.x;
  if (idx < B_ * L_) {
    const int b = idx >> 11;              // idx / L_
    const int v = tok[idx] + 1;
    atomicAdd(&cnt[(size_t)v * B_ + b], 1u);
  }
}

// ---------- K2/K7: vocab-weighted table accumulate ----------
// grid (2, NSLAB), block 256. Block = (col-half, row-slab). Wave w owns
// global cols [half*256 + w*64, +64): one float/lane. LDS acc[64 docs][256
// cols] = 64 KB; wave-owned col slices -> race-free RMW, no atomics.
// USE_CNT: weight = cnt[v][b] (h pass) else wa[v][b] (ct pass).
template <bool USE_CNT>
__global__ __launch_bounds__(256) void k_acc(const unsigned int* __restrict__ cnt,
                                             const float* __restrict__ wa,
                                             const float* __restrict__ emb,
                                             float* __restrict__ part) {
  const int half = blockIdx.x, slab = blockIdx.y;
  const int t = threadIdx.x, w = t >> 6, lane = t & 63;
  __shared__ float acc[B_ * 256];        // exactly 64 KB
  for (int i = t; i < B_ * 256; i += 256) acc[i] = 0.f;
  __syncthreads();
  const int col = half * 256 + w * 64 + lane;   // this lane's table column
  const int r0 = slab * RPB, r1 = (r0 + RPB < VP_) ? r0 + RPB : VP_;
  float* my = acc + w * 64 + lane;              // acc[b*256 + owned-col]
  for (int r = r0; r < r1; ++r) {
    float wgt;
    if (USE_CNT) wgt = (float)cnt[(size_t)r * B_ + lane];
    else         wgt = wa[(size_t)r * B_ + lane];
    unsigned long long mask = __ballot(wgt != 0.f);
    if (!mask) continue;
    const float e = emb[(size_t)r * D_ + col];
    while (mask) {
      const int b = __ffsll((long long)mask) - 1;
      mask &= mask - 1;
      const float wg = __shfl(wgt, b, 64);
      my[b * 256] += wg * e;             // LDS RMW, race-free by ownership
    }
  }
  __syncthreads();
  float* op = part + ((size_t)slab * 2 + half) * (B_ * 256);
  for (int i = t; i < B_ * 256; i += 256) op[i] = acc[i];
}

// ---------- K3/K8: reduce 512 block-partials -> [64][512] ----------
// grid 64 (doc), block 256 (col within half).
__global__ __launch_bounds__(256) void k_red(const float* __restrict__ part,
                                             float* __restrict__ outbuf) {
  const int b = blockIdx.x, t = threadIdx.x;
  float a0 = 0.f, a1 = 0.f;
  for (int s = 0; s < NSLAB; ++s) {
    a0 += part[((size_t)s * 2 + 0) * (B_ * 256) + b * 256 + t];
    a1 += part[((size_t)s * 2 + 1) * (B_ * 256) + b * 256 + t];
  }
  outbuf[(size_t)b * D_ + t]       = a0;
  outbuf[(size_t)b * D_ + 256 + t] = a1;
}

// ---------- K4: v[b] = W_b @ h[b] / L ----------
// grid (8, B_). Same structure as validated round-5 k_v, h read directly.
__global__ __launch_bounds__(256) void k_v(const float* __restrict__ h,
                                           const float* __restrict__ Wb,
                                           float* __restrict__ v) {
  const int g = blockIdx.x, b = blockIdx.y;
  const int t = threadIdx.x, w = t >> 6, lane = t & 63;
  __shared__ float sh[D_];
  sh[t]       = h[(size_t)b * D_ + t];
  sh[t + 256] = h[(size_t)b * D_ + t + 256];
  __syncthreads();
  const float4* shv = (const float4*)sh;
  const float4 a0 = shv[lane];        // cols lane*4 .. +3
  const float4 a1 = shv[lane + 64];   // cols 256+lane*4 .. +3
  const int d0 = g * 64 + w * 16;
#pragma unroll 4
  for (int i = 0; i < 16; ++i) {
    const int d = d0 + i;
    const float4* rp = (const float4*)(Wb + (size_t)d * D_);
    const float4 e0 = rp[lane], e1 = rp[lane + 64];
    float acc = e0.x * a0.x + e0.y * a0.y + e0.z * a0.z + e0.w * a0.w +
                e1.x * a1.x + e1.y * a1.y + e1.z * a1.z + e1.w * a1.w;
    acc = wave_sum(acc);
    if (lane == 0) v[(size_t)b * D_ + d] = acc * (1.f / (float)L_);
  }
}

// ---------- K5: sc[b][v] = T[v].v[b] for active (b,v) only ----------
// grid (2, NSLAB), block 256, wave per row (step 4). Half-row float4/lane;
// V half in LDS (64 KB). Partial dot -> shfl reduce -> atomicAdd into sc
// (the two col-halves sum; sc zeroed by memset).
__global__ __launch_bounds__(256) void k_sc(const unsigned int* __restrict__ cnt,
                                            const float* __restrict__ emb,
                                            const float* __restrict__ v,
                                            float* __restrict__ sc) {
  const int half = blockIdx.x, slab = blockIdx.y;
  const int t = threadIdx.x, w = t >> 6, lane = t & 63;
  __shared__ float V[B_ * 256];          // 64 KB: V[b][c], c within half
  for (int i = t; i < B_ * 256; i += 256) {
    const int b = i >> 8, c = i & 255;
    V[i] = v[(size_t)b * D_ + half * 256 + c];
  }
  __syncthreads();
  const float4* Vv = (const float4*)V;
  const int r0 = slab * RPB, r1 = (r0 + RPB < VP_) ? r0 + RPB : VP_;
  for (int r = r0 + w; r < r1; r += 4) {
    const unsigned cv = cnt[(size_t)r * B_ + lane];
    unsigned long long mask = __ballot(cv != 0);
    if (!mask) continue;
    const float4 e = ((const float4*)(emb + (size_t)r * D_ + half * 256))[lane];
    while (mask) {
      const int b = __ffsll((long long)mask) - 1;
      mask &= mask - 1;
      const float4 vb = Vv[b * 64 + lane];
      float d = e.x * vb.x + e.y * vb.y + e.z * vb.z + e.w * vb.w;
#pragma unroll
      for (int mm = 1; mm < 64; mm <<= 1) d += __shfl_xor(d, mm, 64);
      if (lane == 0) atomicAdd(&sc[(size_t)b * VP_ + r], d);
    }
  }
}

// ---------- K6: gather scores, softmax, scatter weights ----------
// grid B_ (block per doc). Same validated softmax body as round 5.
__global__ __launch_bounds__(256) void k_smax(const int* __restrict__ tok,
                                              const float* __restrict__ sc,
                                              float* __restrict__ wa) {
  const int b = blockIdx.x;
  const int t = threadIdx.x, w = t >> 6, lane = t & 63;
  __shared__ float red[8];
  int tk[8];
  float s[8];
  float m = -1e30f;
#pragma unroll
  for (int k = 0; k < 8; ++k) {
    tk[k] = tok[(size_t)b * L_ + t + 256 * k] + 1;
    s[k] = sc[(size_t)b * VP_ + tk[k]];
    m = fmaxf(m, s[k]);
  }
#pragma unroll
  for (int off = 32; off > 0; off >>= 1) m = fmaxf(m, __shfl_down(m, off, 64));
  if (lane == 0) red[w] = m;
  __syncthreads();
  m = fmaxf(fmaxf(red[0], red[1]), fmaxf(red[2], red[3]));
  float sum = 0.f;
#pragma unroll
  for (int k = 0; k < 8; ++k) { s[k] = __expf(s[k] - m); sum += s[k]; }
  sum = wave_sum(sum);
  if (lane == 0) red[4 + w] = sum;
  __syncthreads();
  const float inv = 1.f / (red[4] + red[5] + red[6] + red[7]);
#pragma unroll
  for (int k = 0; k < 8; ++k)
    atomicAdd(&wa[(size_t)tk[k] * B_ + b], s[k] * inv);   // dup tokens -> atomic
}

// ---------- launch ----------
extern "C" void kernel_launch(void* const* d_in, const int* in_sizes, int n_in,
                              void* d_out, int out_size, void* d_ws, size_t ws_size,
                              hipStream_t stream) {
  const int* tok   = (const int*)d_in[0];
  const float* emb = (const float*)d_in[1];
  const float* Wb  = (const float*)d_in[2];
  float* out = (float*)d_out;
  float* ws  = (float*)d_ws;

  unsigned int* cnt = (unsigned int*)ws;   // [VP_][64] uint
  float* wa   = ws + OFF_WA;               // [VP_][64]
  float* sc   = ws + OFF_SC;               // [64][VP_]
  float* part = ws + OFF_PART;             // [512][64][256]
  float* h    = ws + OFF_H;                // [64][512]
  float* v    = ws + OFF_V;                // [64][512]
  // total ~72.4 MB

  hipMemsetAsync(ws, 0, (size_t)OFF_PART * 4, stream);   // zero cnt, wa, sc
  k_hist     <<<512,             256, 0, stream>>>(tok, cnt);
  k_acc<true><<<dim3(2, NSLAB), 256, 0, stream>>>(cnt, nullptr, emb, part);
  k_red      <<<B_,              256, 0, stream>>>(part, h);
  k_v        <<<dim3(8, B_),     256, 0, stream>>>(h, Wb, v);
  k_sc       <<<dim3(2, NSLAB), 256, 0, stream>>>(cnt, emb, v, sc);
  k_smax     <<<B_,              256, 0, stream>>>(tok, sc, wa);
  k_acc<false><<<dim3(2, NSLAB),256, 0, stream>>>(cnt, wa, emb, part);
  k_red      <<<B_,              256, 0, stream>>>(part, out);
}

// Round 7
// 263.882 us; speedup vs baseline: 2.2427x; 2.2427x over previous
//
#include <hip/hip_runtime.h>

#define B_   64
#define L_   2048
#define D_   512
#define SEG_ 32         // segments over L (2048 blocks per gather pass)
#define RPS_ 64         // rows per segment

// lane0-valid sum
__device__ __forceinline__ float wave_sum(float x) {
#pragma unroll
  for (int off = 32; off > 0; off >>= 1) x += __shfl_down(x, off, 64);
  return x;
}

__device__ __forceinline__ float dot8(float4 e0, float4 e1, float4 a0, float4 a1) {
  return e0.x * a0.x + e0.y * a0.y + e0.z * a0.z + e0.w * a0.w +
         e1.x * a1.x + e1.y * a1.y + e1.z * a1.z + e1.w * a1.w;
}

// ---------- K1: partial sums of embedding rows (for h) ----------
// grid (SEG_, B_) = 2048 blocks, 4 waves. Wave covers a full 512-col fp32
// row (float4 at col lane*4 and 256+lane*4), 16 rows/wave. r3 structure
// (known 75 us at SEG16), no launch_bounds minimum -> no spill.
__global__ __launch_bounds__(256) void k_hpart(const int* __restrict__ tok,
                                               const float* __restrict__ emb,
                                               float* __restrict__ A) {
  const int seg = blockIdx.x, b = blockIdx.y;
  const int t = threadIdx.x, w = t >> 6, lane = t & 63;
  __shared__ int lt[RPS_];
  __shared__ float buf[4 * D_];
  if (t < RPS_) lt[t] = tok[b * L_ + seg * RPS_ + t] + 1;
  __syncthreads();
  float acc[8];
#pragma unroll
  for (int j = 0; j < 8; ++j) acc[j] = 0.f;
#pragma unroll 8
  for (int it = 0; it < RPS_ / 4; ++it) {   // 16 rows per wave
    const int row = lt[it * 4 + w];
    const float4* rp = (const float4*)(emb + (size_t)row * D_);
    const float4 e0 = rp[lane];
    const float4 e1 = rp[lane + 64];
    acc[0] += e0.x; acc[1] += e0.y; acc[2] += e0.z; acc[3] += e0.w;
    acc[4] += e1.x; acc[5] += e1.y; acc[6] += e1.z; acc[7] += e1.w;
  }
#pragma unroll
  for (int j = 0; j < 4; ++j) {
    buf[w * D_ + lane * 4 + j]       = acc[j];
    buf[w * D_ + 256 + lane * 4 + j] = acc[4 + j];
  }
  __syncthreads();
  const int c = 2 * t;
  float s0 = buf[c] + buf[D_ + c] + buf[2 * D_ + c] + buf[3 * D_ + c];
  float s1 = buf[c + 1] + buf[D_ + c + 1] + buf[2 * D_ + c + 1] + buf[3 * D_ + c + 1];
  float* o = A + ((size_t)seg * B_ + b) * D_;
  o[c] = s0; o[c + 1] = s1;
}

// ---------- K2: v[b] = W_b @ h[b] / L ----------
// grid (8, B_) = 512 blocks; reduce 32 h-partials, wave computes 16 rows.
__global__ __launch_bounds__(256) void k_v(const float* __restrict__ A,
                                           const float* __restrict__ Wb,
                                           float* __restrict__ v) {
  const int g = blockIdx.x, b = blockIdx.y;
  const int t = threadIdx.x, w = t >> 6, lane = t & 63;
  __shared__ float sh[D_];
  float s0 = 0.f, s1 = 0.f;
#pragma unroll 8
  for (int s = 0; s < SEG_; ++s) {
    const float* hp = A + ((size_t)s * B_ + b) * D_;
    s0 += hp[2 * t]; s1 += hp[2 * t + 1];
  }
  sh[2 * t] = s0; sh[2 * t + 1] = s1;
  __syncthreads();
  const float4* shv = (const float4*)sh;
  const float4 a0 = shv[lane];        // cols lane*4 .. +3
  const float4 a1 = shv[lane + 64];   // cols 256+lane*4 .. +3
  const int d0 = g * 64 + w * 16;
#pragma unroll 4
  for (int i = 0; i < 16; ++i) {
    const int d = d0 + i;
    const float4* rp = (const float4*)(Wb + (size_t)d * D_);
    float acc = dot8(rp[lane], rp[lane + 64], a0, a1);
    acc = wave_sum(acc);
    if (lane == 0) v[(size_t)b * D_ + d] = acc * (1.f / (float)L_);
  }
}

// ---------- K3: 3-phase scores -> block softmax -> weighted sum ----------
// grid (SEG_, B_) = 2048 blocks. NO online softmax: phase A computes raw
// scores (4 independent shfl chains per group, e dies at the dot); phase B
// one wave reduces block (M, S); phase C re-walks the L2/L3-hot rows with
// pure FMA accumulate (batch 2). Writes per-segment acc at block M + (M,S).
__global__ __launch_bounds__(256) void k_flash(const int* __restrict__ tok,
                                               const float* __restrict__ emb,
                                               const float* __restrict__ v,
                                               float* __restrict__ A,
                                               float* __restrict__ ms) {
  const int seg = blockIdx.x, b = blockIdx.y;
  const int t = threadIdx.x, w = t >> 6, lane = t & 63;
  __shared__ int lt[RPS_];
  __shared__ float sv[D_];
  __shared__ float sS[RPS_];
  __shared__ float MS[2];
  __shared__ float buf[4 * D_];
  if (t < RPS_) lt[t] = tok[b * L_ + seg * RPS_ + t] + 1;
  sv[t] = v[(size_t)b * D_ + t];
  sv[t + 256] = v[(size_t)b * D_ + t + 256];
  __syncthreads();
  const float4* svv = (const float4*)sv;
  const float4 a0 = svv[lane], a1 = svv[lane + 64];

  // ---- phase A: raw scores, 4 rows per group, e transient ----
#pragma unroll
  for (int g = 0; g < 4; ++g) {           // 16 rows per wave
    const int rbase = w * 16 + g * 4;
    float d0, d1, d2, d3;
    {
      const float4* rp0 = (const float4*)(emb + (size_t)lt[rbase + 0] * D_);
      const float4* rp1 = (const float4*)(emb + (size_t)lt[rbase + 1] * D_);
      const float4* rp2 = (const float4*)(emb + (size_t)lt[rbase + 2] * D_);
      const float4* rp3 = (const float4*)(emb + (size_t)lt[rbase + 3] * D_);
      d0 = dot8(rp0[lane], rp0[lane + 64], a0, a1);
      d1 = dot8(rp1[lane], rp1[lane + 64], a0, a1);
      d2 = dot8(rp2[lane], rp2[lane + 64], a0, a1);
      d3 = dot8(rp3[lane], rp3[lane + 64], a0, a1);
    }
#pragma unroll
    for (int mask = 1; mask < 64; mask <<= 1) {   // 4 chains interleaved
      d0 += __shfl_xor(d0, mask, 64);
      d1 += __shfl_xor(d1, mask, 64);
      d2 += __shfl_xor(d2, mask, 64);
      d3 += __shfl_xor(d3, mask, 64);
    }
    if (lane == 0) {
      sS[rbase + 0] = d0; sS[rbase + 1] = d1;
      sS[rbase + 2] = d2; sS[rbase + 3] = d3;
    }
  }
  __syncthreads();

  // ---- phase B: block softmax stats over RPS_=64 scores (wave 0) ----
  if (w == 0) {
    float sc = sS[lane];
    float m = sc;
#pragma unroll
    for (int mask = 1; mask < 64; mask <<= 1) m = fmaxf(m, __shfl_xor(m, mask, 64));
    float p = __expf(sc - m);
#pragma unroll
    for (int mask = 1; mask < 64; mask <<= 1) p += __shfl_xor(p, mask, 64);
    if (lane == 0) { MS[0] = m; MS[1] = p; }
  }
  __syncthreads();
  const float M = MS[0];

  // ---- phase C: acc += p * e, batch 2, no cross-lane ops ----
  float acc[8];
#pragma unroll
  for (int j = 0; j < 8; ++j) acc[j] = 0.f;
#pragma unroll
  for (int g = 0; g < 8; ++g) {           // 8 groups x 2 rows
    const int rbase = w * 16 + g * 2;
    const float p0 = __expf(sS[rbase]     - M);
    const float p1 = __expf(sS[rbase + 1] - M);
    const float4* rp0 = (const float4*)(emb + (size_t)lt[rbase]     * D_);
    const float4* rp1 = (const float4*)(emb + (size_t)lt[rbase + 1] * D_);
    const float4 e00 = rp0[lane], e01 = rp0[lane + 64];
    const float4 e10 = rp1[lane], e11 = rp1[lane + 64];
    acc[0] += p0 * e00.x + p1 * e10.x; acc[1] += p0 * e00.y + p1 * e10.y;
    acc[2] += p0 * e00.z + p1 * e10.z; acc[3] += p0 * e00.w + p1 * e10.w;
    acc[4] += p0 * e01.x + p1 * e11.x; acc[5] += p0 * e01.y + p1 * e11.y;
    acc[6] += p0 * e01.z + p1 * e11.z; acc[7] += p0 * e01.w + p1 * e11.w;
  }
#pragma unroll
  for (int j = 0; j < 4; ++j) {
    buf[w * D_ + lane * 4 + j]       = acc[j];
    buf[w * D_ + 256 + lane * 4 + j] = acc[4 + j];
  }
  __syncthreads();
  const int c = 2 * t;
  float o0 = buf[c] + buf[D_ + c] + buf[2 * D_ + c] + buf[3 * D_ + c];
  float o1 = buf[c + 1] + buf[D_ + c + 1] + buf[2 * D_ + c + 1] + buf[3 * D_ + c + 1];
  float* oa = A + ((size_t)seg * B_ + b) * D_;   // A reuse: k_v already consumed it
  oa[c] = o0; oa[c + 1] = o1;
  if (t == 0) {
    ms[((size_t)seg * B_ + b) * 2]     = MS[0];
    ms[((size_t)seg * B_ + b) * 2 + 1] = MS[1];
  }
}

// ---------- K4: merge segment partials -> out ----------
__global__ __launch_bounds__(256) void k_merge(const float* __restrict__ A,
                                               const float* __restrict__ ms,
                                               float* __restrict__ out) {
  const int b = blockIdx.x;
  const int t = threadIdx.x;
  __shared__ float wseg[SEG_];
  if (t == 0) {
    float M = -1e30f;
#pragma unroll
    for (int s = 0; s < SEG_; ++s) M = fmaxf(M, ms[((size_t)s * B_ + b) * 2]);
    float den = 0.f;
#pragma unroll
    for (int s = 0; s < SEG_; ++s)
      den += ms[((size_t)s * B_ + b) * 2 + 1] * __expf(ms[((size_t)s * B_ + b) * 2] - M);
    const float inv = 1.f / den;
#pragma unroll
    for (int s = 0; s < SEG_; ++s)
      wseg[s] = __expf(ms[((size_t)s * B_ + b) * 2] - M) * inv;
  }
  __syncthreads();
  const int c = 2 * t;
  float o0 = 0.f, o1 = 0.f;
#pragma unroll
  for (int s = 0; s < SEG_; ++s) {
    const float* oa = A + ((size_t)s * B_ + b) * D_;
    const float ww = wseg[s];
    o0 += ww * oa[c]; o1 += ww * oa[c + 1];
  }
  out[(size_t)b * D_ + c] = o0;
  out[(size_t)b * D_ + c + 1] = o1;
}

// ---------- launch ----------
extern "C" void kernel_launch(void* const* d_in, const int* in_sizes, int n_in,
                              void* d_out, int out_size, void* d_ws, size_t ws_size,
                              hipStream_t stream) {
  const int* tok = (const int*)d_in[0];
  const float* emb = (const float*)d_in[1];
  const float* Wb  = (const float*)d_in[2];
  float* out = (float*)d_out;
  float* ws = (float*)d_ws;

  float* A  = ws;               // SEG_*B_*D_ = 1048576 floats (h partials, then flash partials)
  float* v  = ws + 1048576;     // B_*D_ = 32768 floats
  float* ms = ws + 1081344;     // SEG_*B_*2 = 4096 floats   (total ~4.3 MB)

  k_hpart<<<dim3(SEG_, B_), 256, 0, stream>>>(tok, emb, A);
  k_v    <<<dim3(8, B_),    256, 0, stream>>>(A, Wb, v);
  k_flash<<<dim3(SEG_, B_), 256, 0, stream>>>(tok, emb, v, A, ms);
  k_merge<<<B_,             256, 0, stream>>>(A, ms, out);
}

// Round 8
// 262.164 us; speedup vs baseline: 2.2574x; 1.0066x over previous
//
#include <hip/hip_runtime.h>

#define B_   64
#define L_   2048
#define D_   512
#define SEG_ 32         // segments over L (2048 blocks per gather pass)
#define RPS_ 64         // rows per segment

// lane0-valid sum
__device__ __forceinline__ float wave_sum(float x) {
#pragma unroll
  for (int off = 32; off > 0; off >>= 1) x += __shfl_down(x, off, 64);
  return x;
}

__device__ __forceinline__ float dot8(float4 e0, float4 e1, float4 a0, float4 a1) {
  return e0.x * a0.x + e0.y * a0.y + e0.z * a0.z + e0.w * a0.w +
         e1.x * a1.x + e1.y * a1.y + e1.z * a1.z + e1.w * a1.w;
}

// ---------- K1: partial sums of embedding rows (for h) ----------
// grid (SEG_, B_) = 2048 blocks, 4 waves. Flash-phase-A structure: 4 rows
// per group, 8 independent float4 loads in flight, all dying into acc[8].
// (r7's 1-row/iter chain was 175 us cold-HBM latency-bound; flash's 4-row
// batch on the same pattern ran 79 us.) No launch_bounds min -> no spill.
__global__ __launch_bounds__(256) void k_hpart(const int* __restrict__ tok,
                                               const float* __restrict__ emb,
                                               float* __restrict__ A) {
  const int seg = blockIdx.x, b = blockIdx.y;
  const int t = threadIdx.x, w = t >> 6, lane = t & 63;
  __shared__ int lt[RPS_];
  __shared__ float buf[4 * D_];
  if (t < RPS_) lt[t] = tok[b * L_ + seg * RPS_ + t] + 1;
  __syncthreads();
  float acc[8];
#pragma unroll
  for (int j = 0; j < 8; ++j) acc[j] = 0.f;
#pragma unroll
  for (int g = 0; g < 4; ++g) {           // 4 groups x 4 rows = 16 rows/wave
    const int rbase = w * 16 + g * 4;
    const float4* rp0 = (const float4*)(emb + (size_t)lt[rbase + 0] * D_);
    const float4* rp1 = (const float4*)(emb + (size_t)lt[rbase + 1] * D_);
    const float4* rp2 = (const float4*)(emb + (size_t)lt[rbase + 2] * D_);
    const float4* rp3 = (const float4*)(emb + (size_t)lt[rbase + 3] * D_);
    const float4 e00 = rp0[lane], e01 = rp0[lane + 64];
    const float4 e10 = rp1[lane], e11 = rp1[lane + 64];
    const float4 e20 = rp2[lane], e21 = rp2[lane + 64];
    const float4 e30 = rp3[lane], e31 = rp3[lane + 64];
    acc[0] += (e00.x + e10.x) + (e20.x + e30.x);
    acc[1] += (e00.y + e10.y) + (e20.y + e30.y);
    acc[2] += (e00.z + e10.z) + (e20.z + e30.z);
    acc[3] += (e00.w + e10.w) + (e20.w + e30.w);
    acc[4] += (e01.x + e11.x) + (e21.x + e31.x);
    acc[5] += (e01.y + e11.y) + (e21.y + e31.y);
    acc[6] += (e01.z + e11.z) + (e21.z + e31.z);
    acc[7] += (e01.w + e11.w) + (e21.w + e31.w);
  }
#pragma unroll
  for (int j = 0; j < 4; ++j) {
    buf[w * D_ + lane * 4 + j]       = acc[j];
    buf[w * D_ + 256 + lane * 4 + j] = acc[4 + j];
  }
  __syncthreads();
  const int c = 2 * t;
  float s0 = buf[c] + buf[D_ + c] + buf[2 * D_ + c] + buf[3 * D_ + c];
  float s1 = buf[c + 1] + buf[D_ + c + 1] + buf[2 * D_ + c + 1] + buf[3 * D_ + c + 1];
  float* o = A + ((size_t)seg * B_ + b) * D_;
  o[c] = s0; o[c + 1] = s1;
}

// ---------- K2: v[b] = W_b @ h[b] / L ----------
// grid (8, B_) = 512 blocks; reduce 32 h-partials, wave computes 16 rows.
__global__ __launch_bounds__(256) void k_v(const float* __restrict__ A,
                                           const float* __restrict__ Wb,
                                           float* __restrict__ v) {
  const int g = blockIdx.x, b = blockIdx.y;
  const int t = threadIdx.x, w = t >> 6, lane = t & 63;
  __shared__ float sh[D_];
  float s0 = 0.f, s1 = 0.f;
#pragma unroll 8
  for (int s = 0; s < SEG_; ++s) {
    const float* hp = A + ((size_t)s * B_ + b) * D_;
    s0 += hp[2 * t]; s1 += hp[2 * t + 1];
  }
  sh[2 * t] = s0; sh[2 * t + 1] = s1;
  __syncthreads();
  const float4* shv = (const float4*)sh;
  const float4 a0 = shv[lane];        // cols lane*4 .. +3
  const float4 a1 = shv[lane + 64];   // cols 256+lane*4 .. +3
  const int d0 = g * 64 + w * 16;
#pragma unroll 4
  for (int i = 0; i < 16; ++i) {
    const int d = d0 + i;
    const float4* rp = (const float4*)(Wb + (size_t)d * D_);
    float acc = dot8(rp[lane], rp[lane + 64], a0, a1);
    acc = wave_sum(acc);
    if (lane == 0) v[(size_t)b * D_ + d] = acc * (1.f / (float)L_);
  }
}

// ---------- K3: 3-phase scores -> block softmax -> weighted sum ----------
// grid (SEG_, B_) = 2048 blocks. Measured 79 us in r7 — UNCHANGED.
__global__ __launch_bounds__(256) void k_flash(const int* __restrict__ tok,
                                               const float* __restrict__ emb,
                                               const float* __restrict__ v,
                                               float* __restrict__ A,
                                               float* __restrict__ ms) {
  const int seg = blockIdx.x, b = blockIdx.y;
  const int t = threadIdx.x, w = t >> 6, lane = t & 63;
  __shared__ int lt[RPS_];
  __shared__ float sv[D_];
  __shared__ float sS[RPS_];
  __shared__ float MS[2];
  __shared__ float buf[4 * D_];
  if (t < RPS_) lt[t] = tok[b * L_ + seg * RPS_ + t] + 1;
  sv[t] = v[(size_t)b * D_ + t];
  sv[t + 256] = v[(size_t)b * D_ + t + 256];
  __syncthreads();
  const float4* svv = (const float4*)sv;
  const float4 a0 = svv[lane], a1 = svv[lane + 64];

  // ---- phase A: raw scores, 4 rows per group, e transient ----
#pragma unroll
  for (int g = 0; g < 4; ++g) {           // 16 rows per wave
    const int rbase = w * 16 + g * 4;
    float d0, d1, d2, d3;
    {
      const float4* rp0 = (const float4*)(emb + (size_t)lt[rbase + 0] * D_);
      const float4* rp1 = (const float4*)(emb + (size_t)lt[rbase + 1] * D_);
      const float4* rp2 = (const float4*)(emb + (size_t)lt[rbase + 2] * D_);
      const float4* rp3 = (const float4*)(emb + (size_t)lt[rbase + 3] * D_);
      d0 = dot8(rp0[lane], rp0[lane + 64], a0, a1);
      d1 = dot8(rp1[lane], rp1[lane + 64], a0, a1);
      d2 = dot8(rp2[lane], rp2[lane + 64], a0, a1);
      d3 = dot8(rp3[lane], rp3[lane + 64], a0, a1);
    }
#pragma unroll
    for (int mask = 1; mask < 64; mask <<= 1) {   // 4 chains interleaved
      d0 += __shfl_xor(d0, mask, 64);
      d1 += __shfl_xor(d1, mask, 64);
      d2 += __shfl_xor(d2, mask, 64);
      d3 += __shfl_xor(d3, mask, 64);
    }
    if (lane == 0) {
      sS[rbase + 0] = d0; sS[rbase + 1] = d1;
      sS[rbase + 2] = d2; sS[rbase + 3] = d3;
    }
  }
  __syncthreads();

  // ---- phase B: block softmax stats over RPS_=64 scores (wave 0) ----
  if (w == 0) {
    float sc = sS[lane];
    float m = sc;
#pragma unroll
    for (int mask = 1; mask < 64; mask <<= 1) m = fmaxf(m, __shfl_xor(m, mask, 64));
    float p = __expf(sc - m);
#pragma unroll
    for (int mask = 1; mask < 64; mask <<= 1) p += __shfl_xor(p, mask, 64);
    if (lane == 0) { MS[0] = m; MS[1] = p; }
  }
  __syncthreads();
  const float M = MS[0];

  // ---- phase C: acc += p * e, batch 2, no cross-lane ops ----
  float acc[8];
#pragma unroll
  for (int j = 0; j < 8; ++j) acc[j] = 0.f;
#pragma unroll
  for (int g = 0; g < 8; ++g) {           // 8 groups x 2 rows
    const int rbase = w * 16 + g * 2;
    const float p0 = __expf(sS[rbase]     - M);
    const float p1 = __expf(sS[rbase + 1] - M);
    const float4* rp0 = (const float4*)(emb + (size_t)lt[rbase]     * D_);
    const float4* rp1 = (const float4*)(emb + (size_t)lt[rbase + 1] * D_);
    const float4 e00 = rp0[lane], e01 = rp0[lane + 64];
    const float4 e10 = rp1[lane], e11 = rp1[lane + 64];
    acc[0] += p0 * e00.x + p1 * e10.x; acc[1] += p0 * e00.y + p1 * e10.y;
    acc[2] += p0 * e00.z + p1 * e10.z; acc[3] += p0 * e00.w + p1 * e10.w;
    acc[4] += p0 * e01.x + p1 * e11.x; acc[5] += p0 * e01.y + p1 * e11.y;
    acc[6] += p0 * e01.z + p1 * e11.z; acc[7] += p0 * e01.w + p1 * e11.w;
  }
#pragma unroll
  for (int j = 0; j < 4; ++j) {
    buf[w * D_ + lane * 4 + j]       = acc[j];
    buf[w * D_ + 256 + lane * 4 + j] = acc[4 + j];
  }
  __syncthreads();
  const int c = 2 * t;
  float o0 = buf[c] + buf[D_ + c] + buf[2 * D_ + c] + buf[3 * D_ + c];
  float o1 = buf[c + 1] + buf[D_ + c + 1] + buf[2 * D_ + c + 1] + buf[3 * D_ + c + 1];
  float* oa = A + ((size_t)seg * B_ + b) * D_;   // A reuse: k_v already consumed it
  oa[c] = o0; oa[c + 1] = o1;
  if (t == 0) {
    ms[((size_t)seg * B_ + b) * 2]     = MS[0];
    ms[((size_t)seg * B_ + b) * 2 + 1] = MS[1];
  }
}

// ---------- K4: merge segment partials -> out ----------
__global__ __launch_bounds__(256) void k_merge(const float* __restrict__ A,
                                               const float* __restrict__ ms,
                                               float* __restrict__ out) {
  const int b = blockIdx.x;
  const int t = threadIdx.x;
  __shared__ float wseg[SEG_];
  if (t == 0) {
    float M = -1e30f;
#pragma unroll
    for (int s = 0; s < SEG_; ++s) M = fmaxf(M, ms[((size_t)s * B_ + b) * 2]);
    float den = 0.f;
#pragma unroll
    for (int s = 0; s < SEG_; ++s)
      den += ms[((size_t)s * B_ + b) * 2 + 1] * __expf(ms[((size_t)s * B_ + b) * 2] - M);
    const float inv = 1.f / den;
#pragma unroll
    for (int s = 0; s < SEG_; ++s)
      wseg[s] = __expf(ms[((size_t)s * B_ + b) * 2] - M) * inv;
  }
  __syncthreads();
  const int c = 2 * t;
  float o0 = 0.f, o1 = 0.f;
#pragma unroll
  for (int s = 0; s < SEG_; ++s) {
    const float* oa = A + ((size_t)s * B_ + b) * D_;
    const float ww = wseg[s];
    o0 += ww * oa[c]; o1 += ww * oa[c + 1];
  }
  out[(size_t)b * D_ + c] = o0;
  out[(size_t)b * D_ + c + 1] = o1;
}

// ---------- launch ----------
extern "C" void kernel_launch(void* const* d_in, const int* in_sizes, int n_in,
                              void* d_out, int out_size, void* d_ws, size_t ws_size,
                              hipStream_t stream) {
  const int* tok = (const int*)d_in[0];
  const float* emb = (const float*)d_in[1];
  const float* Wb  = (const float*)d_in[2];
  float* out = (float*)d_out;
  float* ws = (float*)d_ws;

  float* A  = ws;               // SEG_*B_*D_ = 1048576 floats (h partials, then flash partials)
  float* v  = ws + 1048576;     // B_*D_ = 32768 floats
  float* ms = ws + 1081344;     // SEG_*B_*2 = 4096 floats   (total ~4.3 MB)

  k_hpart<<<dim3(SEG_, B_), 256, 0, stream>>>(tok, emb, A);
  k_v    <<<dim3(8, B_),    256, 0, stream>>>(A, Wb, v);
  k_flash<<<dim3(SEG_, B_), 256, 0, stream>>>(tok, emb, v, A, ms);
  k_merge<<<B_,             256, 0, stream>>>(A, ms, out);
}